// Round 1
// baseline (5343.113 us; speedup 1.0000x reference)
//
#include <hip/hip_runtime.h>
#include <cmath>

#define SEQLEN 8
#define CH 64  // IN_CH == HID == 64

struct Gate { const float* W; const float* b; float* out; };
struct G3Args {
  const float* A0; const float* A1; const float* A2;
  Gate g[3];
  int n; int accum;
};

// ---- setup: degree + count histogram over rows ----
__global__ __launch_bounds__(256) void edge_hist_kernel(
    const int* __restrict__ ei, const float* __restrict__ ew,
    float* __restrict__ deg, int* __restrict__ cnt, int E) {
  int e = blockIdx.x * 256 + threadIdx.x;
  if (e >= E) return;
  int r = ei[e];
  int c = ei[E + e];
  float wv = (r == c) ? 0.f : ew[e];
  atomicAdd(deg + r, wv);
  atomicAdd(cnt + r, 1);
}

__global__ __launch_bounds__(256) void dinv_kernel(
    const float* __restrict__ deg, float* __restrict__ dinv, int n) {
  int i = blockIdx.x * 256 + threadIdx.x;
  if (i >= n) return;
  float d = deg[i];
  dinv[i] = (d > 0.f) ? (1.0f / sqrtf(d)) : 0.f;
}

// single-block exclusive scan of cnt[0..n) -> row_ptr, woff
__global__ __launch_bounds__(1024) void scan_kernel(
    const int* __restrict__ cnt, int* __restrict__ row_ptr,
    int* __restrict__ woff, int n, int total) {
  __shared__ int sums[1024];
  int tid = threadIdx.x;
  int items = (n + 1023) >> 10;
  int begin = tid * items;
  int s = 0;
  for (int j = 0; j < items; ++j) {
    int idx = begin + j;
    if (idx < n) s += cnt[idx];
  }
  sums[tid] = s;
  __syncthreads();
  if (tid == 0) {
    int run = 0;
    for (int i = 0; i < 1024; ++i) { int t = sums[i]; sums[i] = run; run += t; }
    row_ptr[n] = total;
  }
  __syncthreads();
  int run = sums[tid];
  for (int j = 0; j < items; ++j) {
    int idx = begin + j;
    if (idx < n) { row_ptr[idx] = run; woff[idx] = run; run += cnt[idx]; }
  }
}

__global__ __launch_bounds__(256) void scatter_kernel(
    const int* __restrict__ ei, const float* __restrict__ ew,
    const float* __restrict__ dinv, int* __restrict__ woff,
    int* __restrict__ ccol, float* __restrict__ cwn, int E) {
  int e = blockIdx.x * 256 + threadIdx.x;
  if (e >= E) return;
  int r = ei[e];
  int c = ei[E + e];
  float wv = (r == c) ? 0.f : ew[e];
  float wn = -wv * dinv[r] * dinv[c];
  int pos = atomicAdd(woff + r, 1);
  ccol[pos] = c;
  cwn[pos] = wn;
}

// y[r,:] = alpha * sum_e wn[e]*v[col[e],:]  (+ beta*u[r,:] if beta != 0)
// one wave (64 lanes = 64 channels) per row, 4 rows per block
__global__ __launch_bounds__(256) void spmv_kernel(
    const int* __restrict__ row_ptr, const int* __restrict__ ccol,
    const float* __restrict__ cwn, const float* __restrict__ v,
    const float* __restrict__ u, float* __restrict__ y,
    float alpha, float beta, int n) {
  int r = blockIdx.x * 4 + (threadIdx.x >> 6);
  if (r >= n) return;
  int lane = threadIdx.x & 63;
  int s = row_ptr[r];
  int e = row_ptr[r + 1];
  float acc = 0.f;
  for (int i = s; i < e; ++i) {
    float wv = cwn[i];
    int c = ccol[i];
    acc = fmaf(wv, v[(size_t)c * CH + lane], acc);
  }
  float res = alpha * acc;
  if (beta != 0.f) res += beta * u[(size_t)r * CH + lane];
  y[(size_t)r * CH + lane] = res;
}

// out_g[n,j] = sum_k (A0[n,k]W_g[0][k,j] + A1[n,k]W_g[1][k,j] + A2[n,k]W_g[2][k,j]) + b_g[j]
// blockIdx.y = gate; 64x64 output tile; 4x4 microtile; b128 LDS reads both operands
__global__ __launch_bounds__(256) void gemm3_kernel(G3Args p) {
  __shared__ float At[64 * 68];  // transposed [k][r], stride 68 (16B-aligned, 2-way max)
  __shared__ float Wt[64 * 64];  // [k][c]
  const int gi = blockIdx.y;
  const float* __restrict__ Wg = p.g[gi].W;
  const float* __restrict__ bg = p.g[gi].b;
  float* __restrict__ outg = p.g[gi].out;
  const int n0 = blockIdx.x * 64;
  const int tid = threadIdx.x;
  const int r0 = (tid >> 4) << 2;
  const int c0 = (tid & 15) << 2;
  float acc[4][4];
#pragma unroll
  for (int i = 0; i < 4; ++i)
#pragma unroll
    for (int j = 0; j < 4; ++j) acc[i][j] = 0.f;
  const float* As[3] = { p.A0, p.A1, p.A2 };
  for (int kk = 0; kk < 3; ++kk) {
    const float* __restrict__ A = As[kk];
    const float* __restrict__ Wk = Wg + kk * 4096;
    __syncthreads();
#pragma unroll
    for (int j = 0; j < 4; ++j) {
      int flat = tid + 256 * j;       // 0..1023
      int r = flat >> 4;              // 0..63
      int k4 = (flat & 15) << 2;      // 0..60
      int nn = n0 + r;
      float4 av = (nn < p.n) ? *(const float4*)(A + (size_t)nn * CH + k4)
                             : make_float4(0.f, 0.f, 0.f, 0.f);
      At[(k4 + 0) * 68 + r] = av.x;
      At[(k4 + 1) * 68 + r] = av.y;
      At[(k4 + 2) * 68 + r] = av.z;
      At[(k4 + 3) * 68 + r] = av.w;
      *(float4*)(Wt + flat * 4) = *(const float4*)(Wk + flat * 4);
    }
    __syncthreads();
#pragma unroll 4
    for (int k = 0; k < 64; ++k) {
      float4 a = *(const float4*)(At + k * 68 + r0);
      float4 wv = *(const float4*)(Wt + k * 64 + c0);
      float av4[4] = { a.x, a.y, a.z, a.w };
      float wv4[4] = { wv.x, wv.y, wv.z, wv.w };
#pragma unroll
      for (int i = 0; i < 4; ++i)
#pragma unroll
        for (int j = 0; j < 4; ++j)
          acc[i][j] = fmaf(av4[i], wv4[j], acc[i][j]);
    }
  }
  float4 bv = *(const float4*)(bg + c0);
#pragma unroll
  for (int i = 0; i < 4; ++i) {
    int nn = n0 + r0 + i;
    if (nn < p.n) {
      float* op = outg + (size_t)nn * CH + c0;
      float4 o;
      o.x = acc[i][0] + bv.x;
      o.y = acc[i][1] + bv.y;
      o.z = acc[i][2] + bv.z;
      o.w = acc[i][3] + bv.w;
      if (p.accum) {
        float4 old = *(const float4*)op;
        o.x += old.x; o.y += old.y; o.z += old.z; o.w += old.w;
      }
      *(float4*)op = o;
    }
  }
}

// Z = sigmoid(xz); R = sigmoid(xr); G = H*R; xz <- Z
__global__ __launch_bounds__(256) void ew1_kernel(
    float* __restrict__ xz, const float* __restrict__ xr,
    const float* __restrict__ H, float* __restrict__ G, long long n64) {
  long long i = (long long)blockIdx.x * 256 + threadIdx.x;
  if (i >= n64) return;
  float z = 1.f / (1.f + expf(-xz[i]));
  float r = 1.f / (1.f + expf(-xr[i]));
  G[i] = H[i] * r;
  xz[i] = z;
}

// out = Z*H + (1-Z)*tanh(xh)
__global__ __launch_bounds__(256) void ew2_kernel(
    const float* __restrict__ xz, const float* __restrict__ xh,
    const float* __restrict__ H, float* __restrict__ outt, long long n64) {
  long long i = (long long)blockIdx.x * 256 + threadIdx.x;
  if (i >= n64) return;
  float z = xz[i];
  float ht = tanhf(xh[i]);
  outt[i] = z * H[i] + (1.f - z) * ht;
}

extern "C" void kernel_launch(void* const* d_in, const int* in_sizes, int n_in,
                              void* d_out, int out_size, void* d_ws, size_t ws_size,
                              hipStream_t stream) {
  const float* X    = (const float*)d_in[0];
  const int*   ei   = (const int*)d_in[1];
  const float* ewt  = (const float*)d_in[2];
  const float* W_xz = (const float*)d_in[3];  const float* b_xz = (const float*)d_in[4];
  const float* W_hz = (const float*)d_in[5];  const float* b_hz = (const float*)d_in[6];
  const float* W_xr = (const float*)d_in[7];  const float* b_xr = (const float*)d_in[8];
  const float* W_hr = (const float*)d_in[9];  const float* b_hr = (const float*)d_in[10];
  const float* W_xh = (const float*)d_in[11]; const float* b_xh = (const float*)d_in[12];
  const float* W_hh = (const float*)d_in[13]; const float* b_hh = (const float*)d_in[14];

  const int N = in_sizes[0] / (SEQLEN * CH);
  const int E = in_sizes[1] / 2;
  const size_t NF = (size_t)N * CH;  // elements in one [N,64] slab
  float* out = (float*)d_out;

  char* base = (char*)d_ws;
  size_t off = 0;
  auto take = [&](size_t bytes) -> void* {
    off = (off + 255) & ~(size_t)255;
    void* p = base + off;
    off += bytes;
    return p;
  };
  float* deg   = (float*)take((size_t)N * 4);
  float* dinv  = (float*)take((size_t)N * 4);
  int*   cnt   = (int*)take((size_t)N * 4);
  int*   rowp  = (int*)take((size_t)(N + 1) * 4);
  int*   woff  = (int*)take((size_t)(N + 1) * 4);
  int*   ccol  = (int*)take((size_t)E * 4);
  float* cwn   = (float*)take((size_t)E * 4);
  float* t1    = (float*)take(NF * 4);
  float* t2    = (float*)take(NF * 4);
  float* xz    = (float*)take(NF * 4);
  float* xr    = (float*)take(NF * 4);
  float* xh    = (float*)take(NF * 4);
  float* Gb    = (float*)take(NF * 4);
  float* zeros = (float*)take(NF * 4);
  (void)ws_size; (void)n_in; (void)out_size;

  hipMemsetAsync(deg, 0, (size_t)N * 4, stream);
  hipMemsetAsync(cnt, 0, (size_t)N * 4, stream);
  hipMemsetAsync(zeros, 0, NF * 4, stream);

  const int ebl = (E + 255) / 256;
  const int nbl = (N + 255) / 256;
  edge_hist_kernel<<<ebl, 256, 0, stream>>>(ei, ewt, deg, cnt, E);
  dinv_kernel<<<nbl, 256, 0, stream>>>(deg, dinv, N);
  scan_kernel<<<1, 1024, 0, stream>>>(cnt, rowp, woff, N, E);
  scatter_kernel<<<ebl, 256, 0, stream>>>(ei, ewt, dinv, woff, ccol, cwn, E);

  const dim3 sgrid((N + 3) / 4);
  const int g3x = (N + 63) / 64;
  const int ewbl = (int)((NF + 255) / 256);

  for (int t = 0; t < SEQLEN; ++t) {
    const float* Xt = X + (size_t)t * NF;
    const float* H  = (t == 0) ? zeros : (out + (size_t)(t - 1) * NF);
    float* outt = out + (size_t)t * NF;

    // X-side Chebyshev basis + 3 gate projections (write)
    spmv_kernel<<<sgrid, 256, 0, stream>>>(rowp, ccol, cwn, Xt, Xt, t1, 1.f, 0.f, N);
    spmv_kernel<<<sgrid, 256, 0, stream>>>(rowp, ccol, cwn, t1, Xt, t2, 2.f, -1.f, N);
    G3Args px;
    px.A0 = Xt; px.A1 = t1; px.A2 = t2; px.n = N; px.accum = 0;
    px.g[0] = Gate{ W_xz, b_xz, xz };
    px.g[1] = Gate{ W_xr, b_xr, xr };
    px.g[2] = Gate{ W_xh, b_xh, xh };
    gemm3_kernel<<<dim3(g3x, 3), 256, 0, stream>>>(px);

    // H-side basis + z,r projections (accumulate)
    spmv_kernel<<<sgrid, 256, 0, stream>>>(rowp, ccol, cwn, H, H, t1, 1.f, 0.f, N);
    spmv_kernel<<<sgrid, 256, 0, stream>>>(rowp, ccol, cwn, t1, H, t2, 2.f, -1.f, N);
    G3Args ph;
    ph.A0 = H; ph.A1 = t1; ph.A2 = t2; ph.n = N; ph.accum = 1;
    ph.g[0] = Gate{ W_hz, b_hz, xz };
    ph.g[1] = Gate{ W_hr, b_hr, xr };
    ph.g[2] = Gate{ W_hr, b_hr, xr };  // unused (grid.y = 2)
    gemm3_kernel<<<dim3(g3x, 2), 256, 0, stream>>>(ph);

    ew1_kernel<<<ewbl, 256, 0, stream>>>(xz, xr, H, Gb, (long long)NF);

    // (H*R)-side basis + h projection (accumulate)
    spmv_kernel<<<sgrid, 256, 0, stream>>>(rowp, ccol, cwn, Gb, Gb, t1, 1.f, 0.f, N);
    spmv_kernel<<<sgrid, 256, 0, stream>>>(rowp, ccol, cwn, t1, Gb, t2, 2.f, -1.f, N);
    G3Args pg;
    pg.A0 = Gb; pg.A1 = t1; pg.A2 = t2; pg.n = N; pg.accum = 1;
    pg.g[0] = Gate{ W_hh, b_hh, xh };
    pg.g[1] = pg.g[0]; pg.g[2] = pg.g[0];
    gemm3_kernel<<<dim3(g3x, 1), 256, 0, stream>>>(pg);

    ew2_kernel<<<ewbl, 256, 0, stream>>>(xz, xh, H, outt, (long long)NF);
  }

  // Hlast = States[:, L-1]
  hipMemcpyAsync(out + (size_t)SEQLEN * NF, out + (size_t)(SEQLEN - 1) * NF,
                 NF * 4, hipMemcpyDeviceToDevice, stream);
}

// Round 2
// 2916.454 us; speedup vs baseline: 1.8321x; 1.8321x over previous
//
#include <hip/hip_runtime.h>
#include <cmath>

#define SEQLEN 8
#define CH 64  // IN_CH == HID == 64

struct Gate { const float* W; const float* b; float* out; };
struct G3Args {
  const float* A0; const float* A1; const float* A2;
  Gate g[3];
  int n; int accum;
  long long tstride;  // per-blockIdx.z offset (elements) for A* and g[*].out; 0 when gridDim.z==1
};

// ---- setup: degree + count histogram over rows ----
__global__ __launch_bounds__(256) void edge_hist_kernel(
    const int* __restrict__ ei, const float* __restrict__ ew,
    float* __restrict__ deg, int* __restrict__ cnt, int E) {
  int e = blockIdx.x * 256 + threadIdx.x;
  if (e >= E) return;
  int r = ei[e];
  int c = ei[E + e];
  float wv = (r == c) ? 0.f : ew[e];
  atomicAdd(deg + r, wv);
  atomicAdd(cnt + r, 1);
}

__global__ __launch_bounds__(256) void dinv_kernel(
    const float* __restrict__ deg, float* __restrict__ dinv, int n) {
  int i = blockIdx.x * 256 + threadIdx.x;
  if (i >= n) return;
  float d = deg[i];
  dinv[i] = (d > 0.f) ? (1.0f / sqrtf(d)) : 0.f;
}

// ---- hierarchical scan (replaces 132us single-block serial scan) ----
// k1: per-256-chunk sums (coalesced)
__global__ __launch_bounds__(256) void scan_part_kernel(
    const int* __restrict__ cnt, int* __restrict__ bsum, int n) {
  int i = blockIdx.x * 256 + threadIdx.x;
  int v = (i < n) ? cnt[i] : 0;
#pragma unroll
  for (int o = 32; o; o >>= 1) v += __shfl_down(v, o, 64);
  __shared__ int red[4];
  if ((threadIdx.x & 63) == 0) red[threadIdx.x >> 6] = v;
  __syncthreads();
  if (threadIdx.x == 0) bsum[blockIdx.x] = red[0] + red[1] + red[2] + red[3];
}

// k2: exclusive scan of block sums in-place (nb <= 256; N=50000 -> nb=196)
__global__ __launch_bounds__(256) void scan_top_kernel(int* __restrict__ bsum, int nb) {
  int tid = threadIdx.x, lane = tid & 63, wid = tid >> 6;
  int v = (tid < nb) ? bsum[tid] : 0;
  int orig = v;
#pragma unroll
  for (int o = 1; o < 64; o <<= 1) { int t = __shfl_up(v, o, 64); if (lane >= o) v += t; }
  __shared__ int wsum[4];
  if (lane == 63) wsum[wid] = v;
  __syncthreads();
  int base = 0;
  for (int w = 0; w < wid; ++w) base += wsum[w];
  if (tid < nb) bsum[tid] = base + v - orig;
}

// k3: per-chunk exclusive scan + block offset -> row_ptr/woff
__global__ __launch_bounds__(256) void scan_fill_kernel(
    const int* __restrict__ cnt, const int* __restrict__ bsum,
    int* __restrict__ rowp, int* __restrict__ woff, int n, int total) {
  int i = blockIdx.x * 256 + threadIdx.x;
  int tid = threadIdx.x, lane = tid & 63, wid = tid >> 6;
  int v = (i < n) ? cnt[i] : 0;
  int orig = v;
#pragma unroll
  for (int o = 1; o < 64; o <<= 1) { int t = __shfl_up(v, o, 64); if (lane >= o) v += t; }
  __shared__ int wsum[4];
  if (lane == 63) wsum[wid] = v;
  __syncthreads();
  int base = bsum[blockIdx.x];
  for (int w = 0; w < wid; ++w) base += wsum[w];
  if (i < n) { int ex = base + v - orig; rowp[i] = ex; woff[i] = ex; }
  if (blockIdx.x == 0 && tid == 0) rowp[n] = total;
}

__global__ __launch_bounds__(256) void scatter_kernel(
    const int* __restrict__ ei, const float* __restrict__ ew,
    const float* __restrict__ dinv, int* __restrict__ woff,
    int* __restrict__ ccol, float* __restrict__ cwn, int E) {
  int e = blockIdx.x * 256 + threadIdx.x;
  if (e >= E) return;
  int r = ei[e];
  int c = ei[E + e];
  float wv = (r == c) ? 0.f : ew[e];
  float wn = -wv * dinv[r] * dinv[c];
  int pos = atomicAdd(woff + r, 1);
  ccol[pos] = c;
  cwn[pos] = wn;
}

// y[r,:] = alpha * sum_e wn[e]*v[col[e],:]  (+ beta*u[r,:] if beta != 0)
// one wave per row; blockIdx.y selects slab (stride elements) for multi-timestep batching.
// Edge loop unrolled x4 with independent gathers in flight; row bounds readfirstlane'd
// so edge-stream addressing is wave-uniform (scalar-cache eligible).
__global__ __launch_bounds__(256) void spmv_kernel(
    const int* __restrict__ rowp, const int* __restrict__ ccol,
    const float* __restrict__ cwn, const float* __restrict__ v,
    const float* __restrict__ u, float* __restrict__ y,
    float alpha, float beta, int n, long long slab_stride) {
  int r = blockIdx.x * 4 + (threadIdx.x >> 6);
  if (r >= n) return;
  long long so = (long long)blockIdx.y * slab_stride;
  const float* __restrict__ vs = v + so;
  const float* __restrict__ us = u + so;
  float* __restrict__ ys = y + so;
  int lane = threadIdx.x & 63;
  int s = __builtin_amdgcn_readfirstlane(rowp[r]);
  int e = __builtin_amdgcn_readfirstlane(rowp[r + 1]);
  float a0 = 0.f, a1 = 0.f, a2 = 0.f, a3 = 0.f;
  int i = s;
  for (; i + 4 <= e; i += 4) {
    int c0 = ccol[i], c1 = ccol[i + 1], c2 = ccol[i + 2], c3 = ccol[i + 3];
    float w0 = cwn[i], w1 = cwn[i + 1], w2 = cwn[i + 2], w3 = cwn[i + 3];
    float x0 = vs[(size_t)c0 * CH + lane];
    float x1 = vs[(size_t)c1 * CH + lane];
    float x2 = vs[(size_t)c2 * CH + lane];
    float x3 = vs[(size_t)c3 * CH + lane];
    a0 = fmaf(w0, x0, a0); a1 = fmaf(w1, x1, a1);
    a2 = fmaf(w2, x2, a2); a3 = fmaf(w3, x3, a3);
  }
  for (; i < e; ++i) a0 = fmaf(cwn[i], vs[(size_t)ccol[i] * CH + lane], a0);
  float res = alpha * ((a0 + a1) + (a2 + a3));
  if (beta != 0.f) res += beta * us[(size_t)r * CH + lane];
  ys[(size_t)r * CH + lane] = res;
}

// out_g[n,j] = sum_kk A_kk[n,:] @ W_g[kk][:,j] + b_g[j]; blockIdx.y = gate, blockIdx.z = timestep
__global__ __launch_bounds__(256) void gemm3_kernel(G3Args p) {
  __shared__ float At[64 * 68];  // transposed [k][r], stride 68
  __shared__ float Wt[64 * 64];  // [k][c]
  const int gi = blockIdx.y;
  const long long toff = (long long)blockIdx.z * p.tstride;
  const float* __restrict__ Wg = p.g[gi].W;
  const float* __restrict__ bg = p.g[gi].b;
  float* __restrict__ outg = p.g[gi].out + toff;
  const int n0 = blockIdx.x * 64;
  const int tid = threadIdx.x;
  const int r0 = (tid >> 4) << 2;
  const int c0 = (tid & 15) << 2;
  float acc[4][4];
#pragma unroll
  for (int i = 0; i < 4; ++i)
#pragma unroll
    for (int j = 0; j < 4; ++j) acc[i][j] = 0.f;
  const float* As[3] = { p.A0 + toff, p.A1 + toff, p.A2 + toff };
  for (int kk = 0; kk < 3; ++kk) {
    const float* __restrict__ A = As[kk];
    const float* __restrict__ Wk = Wg + kk * 4096;
    __syncthreads();
#pragma unroll
    for (int j = 0; j < 4; ++j) {
      int flat = tid + 256 * j;       // 0..1023
      int r = flat >> 4;              // 0..63
      int k4 = (flat & 15) << 2;      // 0..60
      int nn = n0 + r;
      float4 av = (nn < p.n) ? *(const float4*)(A + (size_t)nn * CH + k4)
                             : make_float4(0.f, 0.f, 0.f, 0.f);
      At[(k4 + 0) * 68 + r] = av.x;
      At[(k4 + 1) * 68 + r] = av.y;
      At[(k4 + 2) * 68 + r] = av.z;
      At[(k4 + 3) * 68 + r] = av.w;
      *(float4*)(Wt + flat * 4) = *(const float4*)(Wk + flat * 4);
    }
    __syncthreads();
#pragma unroll 4
    for (int k = 0; k < 64; ++k) {
      float4 a = *(const float4*)(At + k * 68 + r0);
      float4 wv = *(const float4*)(Wt + k * 64 + c0);
      float av4[4] = { a.x, a.y, a.z, a.w };
      float wv4[4] = { wv.x, wv.y, wv.z, wv.w };
#pragma unroll
      for (int i = 0; i < 4; ++i)
#pragma unroll
        for (int j = 0; j < 4; ++j)
          acc[i][j] = fmaf(av4[i], wv4[j], acc[i][j]);
    }
  }
  float4 bv = *(const float4*)(bg + c0);
#pragma unroll
  for (int i = 0; i < 4; ++i) {
    int nn = n0 + r0 + i;
    if (nn < p.n) {
      float* op = outg + (size_t)nn * CH + c0;
      float4 o;
      o.x = acc[i][0] + bv.x;
      o.y = acc[i][1] + bv.y;
      o.z = acc[i][2] + bv.z;
      o.w = acc[i][3] + bv.w;
      if (p.accum) {
        float4 old = *(const float4*)op;
        o.x += old.x; o.y += old.y; o.z += old.z; o.w += old.w;
      }
      *(float4*)op = o;
    }
  }
}

// Z = sigmoid(xz); R = sigmoid(xr); G = H*R; xz <- Z  (float4)
__global__ __launch_bounds__(256) void ew1_kernel(
    float4* __restrict__ xz, const float4* __restrict__ xr,
    const float4* __restrict__ H, float4* __restrict__ G, int n4) {
  int i = blockIdx.x * 256 + threadIdx.x;
  if (i >= n4) return;
  float4 z4 = xz[i], r4 = xr[i], h4 = H[i];
  float4 zo, go;
  zo.x = 1.f / (1.f + expf(-z4.x)); zo.y = 1.f / (1.f + expf(-z4.y));
  zo.z = 1.f / (1.f + expf(-z4.z)); zo.w = 1.f / (1.f + expf(-z4.w));
  go.x = h4.x / (1.f + expf(r4.x * -1.f) ) * 0.f; // placeholder removed below
  float rx = 1.f / (1.f + expf(-r4.x)), ry = 1.f / (1.f + expf(-r4.y));
  float rz = 1.f / (1.f + expf(-r4.z)), rw = 1.f / (1.f + expf(-r4.w));
  go.x = h4.x * rx; go.y = h4.y * ry; go.z = h4.z * rz; go.w = h4.w * rw;
  G[i] = go;
  xz[i] = zo;
}

// out = Z*H + (1-Z)*tanh(xh)  (float4)
__global__ __launch_bounds__(256) void ew2_kernel(
    const float4* __restrict__ xz, const float4* __restrict__ xh,
    const float4* __restrict__ H, float4* __restrict__ outt, int n4) {
  int i = blockIdx.x * 256 + threadIdx.x;
  if (i >= n4) return;
  float4 z4 = xz[i], g4 = xh[i], h4 = H[i];
  float4 o;
  o.x = z4.x * h4.x + (1.f - z4.x) * tanhf(g4.x);
  o.y = z4.y * h4.y + (1.f - z4.y) * tanhf(g4.y);
  o.z = z4.z * h4.z + (1.f - z4.z) * tanhf(g4.z);
  o.w = z4.w * h4.w + (1.f - z4.w) * tanhf(g4.w);
  outt[i] = o;
}

extern "C" void kernel_launch(void* const* d_in, const int* in_sizes, int n_in,
                              void* d_out, int out_size, void* d_ws, size_t ws_size,
                              hipStream_t stream) {
  const float* X    = (const float*)d_in[0];
  const int*   ei   = (const int*)d_in[1];
  const float* ewt  = (const float*)d_in[2];
  const float* W_xz = (const float*)d_in[3];  const float* b_xz = (const float*)d_in[4];
  const float* W_hz = (const float*)d_in[5];  const float* b_hz = (const float*)d_in[6];
  const float* W_xr = (const float*)d_in[7];  const float* b_xr = (const float*)d_in[8];
  const float* W_hr = (const float*)d_in[9];  const float* b_hr = (const float*)d_in[10];
  const float* W_xh = (const float*)d_in[11]; const float* b_xh = (const float*)d_in[12];
  const float* W_hh = (const float*)d_in[13]; const float* b_hh = (const float*)d_in[14];

  const int N = in_sizes[0] / (SEQLEN * CH);
  const int E = in_sizes[1] / 2;
  const size_t NF = (size_t)N * CH;
  float* out = (float*)d_out;

  char* base = (char*)d_ws;
  size_t off = 0;
  auto take = [&](size_t bytes) -> void* {
    off = (off + 255) & ~(size_t)255;
    void* p = base + off;
    off += bytes;
    return p;
  };
  float* deg   = (float*)take((size_t)N * 4);
  float* dinv  = (float*)take((size_t)N * 4);
  int*   cnt   = (int*)take((size_t)N * 4);
  int*   rowp  = (int*)take((size_t)(N + 1) * 4);
  int*   woff  = (int*)take((size_t)(N + 1) * 4);
  int*   bsum  = (int*)take(1024 * 4);
  int*   ccol  = (int*)take((size_t)E * 4);
  float* cwn   = (float*)take((size_t)E * 4);
  float* t1    = (float*)take(NF * 4);
  float* t2    = (float*)take(NF * 4);
  float* xz    = (float*)take(NF * 4);
  float* xr    = (float*)take(NF * 4);
  float* xh    = (float*)take(NF * 4);
  float* Gb    = (float*)take(NF * 4);
  float* zeros = (float*)take(NF * 4);
  size_t off_base = off;
  // tier1: batched X-side Chebyshev bases
  float* t1x = (float*)take(NF * 4 * SEQLEN);
  float* t2x = (float*)take(NF * 4 * SEQLEN);
  size_t off_t1 = off;
  // tier2: batched X-side gate projections
  float* xza = (float*)take(NF * 4 * SEQLEN);
  float* xra = (float*)take(NF * 4 * SEQLEN);
  float* xha = (float*)take(NF * 4 * SEQLEN);
  size_t off_t2 = off;
  (void)off_base; (void)n_in; (void)out_size;
  const int tier = (off_t2 <= ws_size) ? 2 : (off_t1 <= ws_size) ? 1 : 0;

  hipMemsetAsync(deg, 0, (size_t)N * 4, stream);
  hipMemsetAsync(cnt, 0, (size_t)N * 4, stream);
  hipMemsetAsync(zeros, 0, NF * 4, stream);

  const int ebl = (E + 255) / 256;
  const int nbl = (N + 255) / 256;
  edge_hist_kernel<<<ebl, 256, 0, stream>>>(ei, ewt, deg, cnt, E);
  dinv_kernel<<<nbl, 256, 0, stream>>>(deg, dinv, N);
  scan_part_kernel<<<nbl, 256, 0, stream>>>(cnt, bsum, N);
  scan_top_kernel<<<1, 256, 0, stream>>>(bsum, nbl);
  scan_fill_kernel<<<nbl, 256, 0, stream>>>(cnt, bsum, rowp, woff, N, E);
  scatter_kernel<<<ebl, 256, 0, stream>>>(ei, ewt, dinv, woff, ccol, cwn, E);

  const int nq = (N + 3) / 4;
  const int g3x = (N + 63) / 64;
  const int n4 = (int)(NF / 4);
  const int ewbl = (n4 + 255) / 256;

  if (tier >= 1) {
    // all-timestep X-side bases in 2 launches
    spmv_kernel<<<dim3(nq, SEQLEN), 256, 0, stream>>>(
        rowp, ccol, cwn, X, X, t1x, 1.f, 0.f, N, (long long)NF);
    spmv_kernel<<<dim3(nq, SEQLEN), 256, 0, stream>>>(
        rowp, ccol, cwn, t1x, X, t2x, 2.f, -1.f, N, (long long)NF);
  }
  if (tier == 2) {
    // all-timestep x-gate projections in 1 launch
    G3Args px;
    px.A0 = X; px.A1 = t1x; px.A2 = t2x; px.n = N; px.accum = 0;
    px.tstride = (long long)NF;
    px.g[0] = Gate{ W_xz, b_xz, xza };
    px.g[1] = Gate{ W_xr, b_xr, xra };
    px.g[2] = Gate{ W_xh, b_xh, xha };
    gemm3_kernel<<<dim3(g3x, 3, SEQLEN), 256, 0, stream>>>(px);
  }

  for (int t = 0; t < SEQLEN; ++t) {
    const float* Xt = X + (size_t)t * NF;
    const float* H  = (t == 0) ? zeros : (out + (size_t)(t - 1) * NF);
    float* outt = out + (size_t)t * NF;
    float* xzt = (tier == 2) ? (xza + (size_t)t * NF) : xz;
    float* xrt = (tier == 2) ? (xra + (size_t)t * NF) : xr;
    float* xht = (tier == 2) ? (xha + (size_t)t * NF) : xh;

    if (tier < 2) {
      const float* A1 = (tier == 1) ? (t1x + (size_t)t * NF) : t1;
      const float* A2 = (tier == 1) ? (t2x + (size_t)t * NF) : t2;
      if (tier == 0) {
        spmv_kernel<<<dim3(nq, 1), 256, 0, stream>>>(rowp, ccol, cwn, Xt, Xt, t1, 1.f, 0.f, N, 0);
        spmv_kernel<<<dim3(nq, 1), 256, 0, stream>>>(rowp, ccol, cwn, t1, Xt, t2, 2.f, -1.f, N, 0);
      }
      G3Args px;
      px.A0 = Xt; px.A1 = A1; px.A2 = A2; px.n = N; px.accum = 0; px.tstride = 0;
      px.g[0] = Gate{ W_xz, b_xz, xzt };
      px.g[1] = Gate{ W_xr, b_xr, xrt };
      px.g[2] = Gate{ W_xh, b_xh, xht };
      gemm3_kernel<<<dim3(g3x, 3, 1), 256, 0, stream>>>(px);
    }

    // H-side basis + z,r projections (accumulate)
    spmv_kernel<<<dim3(nq, 1), 256, 0, stream>>>(rowp, ccol, cwn, H, H, t1, 1.f, 0.f, N, 0);
    spmv_kernel<<<dim3(nq, 1), 256, 0, stream>>>(rowp, ccol, cwn, t1, H, t2, 2.f, -1.f, N, 0);
    G3Args ph;
    ph.A0 = H; ph.A1 = t1; ph.A2 = t2; ph.n = N; ph.accum = 1; ph.tstride = 0;
    ph.g[0] = Gate{ W_hz, b_hz, xzt };
    ph.g[1] = Gate{ W_hr, b_hr, xrt };
    ph.g[2] = ph.g[1];  // unused (grid.y = 2)
    gemm3_kernel<<<dim3(g3x, 2, 1), 256, 0, stream>>>(ph);

    ew1_kernel<<<ewbl, 256, 0, stream>>>((float4*)xzt, (const float4*)xrt,
                                         (const float4*)H, (float4*)Gb, n4);

    // (H*R)-side basis + h projection (accumulate)
    spmv_kernel<<<dim3(nq, 1), 256, 0, stream>>>(rowp, ccol, cwn, Gb, Gb, t1, 1.f, 0.f, N, 0);
    spmv_kernel<<<dim3(nq, 1), 256, 0, stream>>>(rowp, ccol, cwn, t1, Gb, t2, 2.f, -1.f, N, 0);
    G3Args pg;
    pg.A0 = Gb; pg.A1 = t1; pg.A2 = t2; pg.n = N; pg.accum = 1; pg.tstride = 0;
    pg.g[0] = Gate{ W_hh, b_hh, xht };
    pg.g[1] = pg.g[0]; pg.g[2] = pg.g[0];
    gemm3_kernel<<<dim3(g3x, 1, 1), 256, 0, stream>>>(pg);

    ew2_kernel<<<ewbl, 256, 0, stream>>>((const float4*)xzt, (const float4*)xht,
                                         (const float4*)H, (float4*)outt, n4);
  }

  // Hlast = States[:, L-1]
  hipMemcpyAsync(out + (size_t)SEQLEN * NF, out + (size_t)(SEQLEN - 1) * NF,
                 NF * 4, hipMemcpyDeviceToDevice, stream);
}

// Round 3
// 2745.655 us; speedup vs baseline: 1.9460x; 1.0622x over previous
//
#include <hip/hip_runtime.h>
#include <cmath>

#define SEQLEN 8
#define CH 64  // IN_CH == HID == 64

// ---- setup: degree + count histogram over rows ----
__global__ __launch_bounds__(256) void edge_hist_kernel(
    const int* __restrict__ ei, const float* __restrict__ ew,
    float* __restrict__ deg, int* __restrict__ cnt, int E) {
  int e = blockIdx.x * 256 + threadIdx.x;
  if (e >= E) return;
  int r = ei[e];
  int c = ei[E + e];
  float wv = (r == c) ? 0.f : ew[e];
  atomicAdd(deg + r, wv);
  atomicAdd(cnt + r, 1);
}

__global__ __launch_bounds__(256) void dinv_kernel(
    const float* __restrict__ deg, float* __restrict__ dinv, int n) {
  int i = blockIdx.x * 256 + threadIdx.x;
  if (i >= n) return;
  float d = deg[i];
  dinv[i] = (d > 0.f) ? (1.0f / sqrtf(d)) : 0.f;
}

// ---- hierarchical scan ----
__global__ __launch_bounds__(256) void scan_part_kernel(
    const int* __restrict__ cnt, int* __restrict__ bsum, int n) {
  int i = blockIdx.x * 256 + threadIdx.x;
  int v = (i < n) ? cnt[i] : 0;
#pragma unroll
  for (int o = 32; o; o >>= 1) v += __shfl_down(v, o, 64);
  __shared__ int red[4];
  if ((threadIdx.x & 63) == 0) red[threadIdx.x >> 6] = v;
  __syncthreads();
  if (threadIdx.x == 0) bsum[blockIdx.x] = red[0] + red[1] + red[2] + red[3];
}

__global__ __launch_bounds__(256) void scan_top_kernel(int* __restrict__ bsum, int nb) {
  int tid = threadIdx.x, lane = tid & 63, wid = tid >> 6;
  int v = (tid < nb) ? bsum[tid] : 0;
  int orig = v;
#pragma unroll
  for (int o = 1; o < 64; o <<= 1) { int t = __shfl_up(v, o, 64); if (lane >= o) v += t; }
  __shared__ int wsum[4];
  if (lane == 63) wsum[wid] = v;
  __syncthreads();
  int base = 0;
  for (int w = 0; w < wid; ++w) base += wsum[w];
  if (tid < nb) bsum[tid] = base + v - orig;
}

__global__ __launch_bounds__(256) void scan_fill_kernel(
    const int* __restrict__ cnt, const int* __restrict__ bsum,
    int* __restrict__ rowp, int* __restrict__ woff, int n, int total) {
  int i = blockIdx.x * 256 + threadIdx.x;
  int tid = threadIdx.x, lane = tid & 63, wid = tid >> 6;
  int v = (i < n) ? cnt[i] : 0;
  int orig = v;
#pragma unroll
  for (int o = 1; o < 64; o <<= 1) { int t = __shfl_up(v, o, 64); if (lane >= o) v += t; }
  __shared__ int wsum[4];
  if (lane == 63) wsum[wid] = v;
  __syncthreads();
  int base = bsum[blockIdx.x];
  for (int w = 0; w < wid; ++w) base += wsum[w];
  if (i < n) { int ex = base + v - orig; rowp[i] = ex; woff[i] = ex; }
  if (blockIdx.x == 0 && tid == 0) rowp[n] = total;
}

__global__ __launch_bounds__(256) void scatter_kernel(
    const int* __restrict__ ei, const float* __restrict__ ew,
    const float* __restrict__ dinv, int* __restrict__ woff,
    int* __restrict__ ccol, float* __restrict__ cwn, int E) {
  int e = blockIdx.x * 256 + threadIdx.x;
  if (e >= E) return;
  int r = ei[e];
  int c = ei[E + e];
  float wv = (r == c) ? 0.f : ew[e];
  float wn = -wv * dinv[r] * dinv[c];
  int pos = atomicAdd(woff + r, 1);
  ccol[pos] = c;
  cwn[pos] = wn;
}

// y[r,:] = alpha * sum_e wn[e]*v[col[e],:]  (+ beta*u[r,:] if beta != 0)
__global__ __launch_bounds__(256) void spmv_kernel(
    const int* __restrict__ rowp, const int* __restrict__ ccol,
    const float* __restrict__ cwn, const float* __restrict__ v,
    const float* __restrict__ u, float* __restrict__ y,
    float alpha, float beta, int n, long long slab_stride) {
  int r = blockIdx.x * 4 + (threadIdx.x >> 6);
  if (r >= n) return;
  long long so = (long long)blockIdx.y * slab_stride;
  const float* __restrict__ vs = v + so;
  const float* __restrict__ us = u + so;
  float* __restrict__ ys = y + so;
  int lane = threadIdx.x & 63;
  int s = __builtin_amdgcn_readfirstlane(rowp[r]);
  int e = __builtin_amdgcn_readfirstlane(rowp[r + 1]);
  float a0 = 0.f, a1 = 0.f, a2 = 0.f, a3 = 0.f;
  int i = s;
  for (; i + 4 <= e; i += 4) {
    int c0 = ccol[i], c1 = ccol[i + 1], c2 = ccol[i + 2], c3 = ccol[i + 3];
    float w0 = cwn[i], w1 = cwn[i + 1], w2 = cwn[i + 2], w3 = cwn[i + 3];
    float x0 = vs[(size_t)c0 * CH + lane];
    float x1 = vs[(size_t)c1 * CH + lane];
    float x2 = vs[(size_t)c2 * CH + lane];
    float x3 = vs[(size_t)c3 * CH + lane];
    a0 = fmaf(w0, x0, a0); a1 = fmaf(w1, x1, a1);
    a2 = fmaf(w2, x2, a2); a3 = fmaf(w3, x3, a3);
  }
  for (; i < e; ++i) a0 = fmaf(cwn[i], vs[(size_t)ccol[i] * CH + lane], a0);
  float res = alpha * ((a0 + a1) + (a2 + a3));
  if (beta != 0.f) res += beta * us[(size_t)r * CH + lane];
  ys[(size_t)r * CH + lane] = res;
}

// ---- fused multi-gate GEMM ----
// Computes, per gate g: acc_g[n, j] = sum_kk A[kk][n,:] @ W[g][kk][:,j]
// A-tile staged ONCE per k-block, reused across gates (only W re-staged).
// MODE 0: out[g] = acc_g + b[g]                      (X-side partials)
// MODE 1: Z=sig(P0+b0+acc0); R=sig(P1+b1+acc1); O0=Z, O1=H*R
// MODE 2: T=tanh(P0+b0+acc0); O0 = Z*H + (1-Z)*T
struct FG {
  const float* A[3];
  const float* W[3];
  const float* Bv[3];
  const float* P[3];
  const float* Hb;
  const float* Zb;
  float* O[3];
  int n;
  long long tstride;  // per-blockIdx.z offset for A[] and O[] (MODE 0 batched)
};

__device__ __forceinline__ void fma_tile(float (&acc)[4][4], const float* At,
                                         const float* Wt, int r0, int c0) {
#pragma unroll 4
  for (int k = 0; k < 64; ++k) {
    float4 a = *(const float4*)(At + k * 68 + r0);
    float4 w = *(const float4*)(Wt + k * 64 + c0);
    float av[4] = { a.x, a.y, a.z, a.w };
    float wv[4] = { w.x, w.y, w.z, w.w };
#pragma unroll
    for (int i = 0; i < 4; ++i)
#pragma unroll
      for (int j = 0; j < 4; ++j)
        acc[i][j] = fmaf(av[i], wv[j], acc[i][j]);
  }
}

__device__ __forceinline__ float sigf(float x) { return 1.f / (1.f + expf(-x)); }

template <int MODE, int G>
__global__ __launch_bounds__(256) void gemmf_kernel(FG p) {
  __shared__ float At[64 * 68];  // [k][r], stride 68 (16B aligned)
  __shared__ float Wt[64 * 64];  // [k][c]
  const int tid = threadIdx.x;
  const int n0 = blockIdx.x * 64;
  const int r0 = (tid >> 4) << 2;
  const int c0 = (tid & 15) << 2;
  const long long toff = (long long)blockIdx.z * p.tstride;
  float acc[G][4][4];
#pragma unroll
  for (int g = 0; g < G; ++g)
#pragma unroll
    for (int i = 0; i < 4; ++i)
#pragma unroll
      for (int j = 0; j < 4; ++j) acc[g][i][j] = 0.f;

  for (int kk = 0; kk < 3; ++kk) {
    const float* __restrict__ A = p.A[kk] + toff;
    __syncthreads();  // prior k-block reads complete
#pragma unroll
    for (int j = 0; j < 4; ++j) {
      int flat = tid + 256 * j;
      int r = flat >> 4;
      int k4 = (flat & 15) << 2;
      int nn = n0 + r;
      float4 av = (nn < p.n) ? *(const float4*)(A + (size_t)nn * CH + k4)
                             : make_float4(0.f, 0.f, 0.f, 0.f);
      At[(k4 + 0) * 68 + r] = av.x;
      At[(k4 + 1) * 68 + r] = av.y;
      At[(k4 + 2) * 68 + r] = av.z;
      At[(k4 + 3) * 68 + r] = av.w;
    }
#pragma unroll
    for (int g = 0; g < G; ++g) {
      if (g > 0) __syncthreads();  // gate g-1 done reading Wt
      const float* __restrict__ Wk = p.W[g] + kk * 4096;
#pragma unroll
      for (int j = 0; j < 4; ++j) {
        int flat = tid + 256 * j;
        *(float4*)(Wt + flat * 4) = *(const float4*)(Wk + flat * 4);
      }
      __syncthreads();
      fma_tile(acc[g], At, Wt, r0, c0);
    }
  }

  if (MODE == 0) {
#pragma unroll
    for (int g = 0; g < G; ++g) {
      float4 bv = *(const float4*)(p.Bv[g] + c0);
      float* og = p.O[g] + toff;
#pragma unroll
      for (int i = 0; i < 4; ++i) {
        int nn = n0 + r0 + i;
        if (nn < p.n) {
          float4 o;
          o.x = acc[g][i][0] + bv.x;
          o.y = acc[g][i][1] + bv.y;
          o.z = acc[g][i][2] + bv.z;
          o.w = acc[g][i][3] + bv.w;
          *(float4*)(og + (size_t)nn * CH + c0) = o;
        }
      }
    }
  } else if (MODE == 1) {
    float4 bz = *(const float4*)(p.Bv[0] + c0);
    float4 br = *(const float4*)(p.Bv[1] + c0);
#pragma unroll
    for (int i = 0; i < 4; ++i) {
      int nn = n0 + r0 + i;
      if (nn < p.n) {
        size_t idx = (size_t)nn * CH + c0;
        float4 pz = *(const float4*)(p.P[0] + idx);
        float4 pr = *(const float4*)(p.P[1] + idx);
        float4 h4 = *(const float4*)(p.Hb + idx);
        float4 z, gg;
        z.x = sigf(pz.x + bz.x + acc[0][i][0]);
        z.y = sigf(pz.y + bz.y + acc[0][i][1]);
        z.z = sigf(pz.z + bz.z + acc[0][i][2]);
        z.w = sigf(pz.w + bz.w + acc[0][i][3]);
        gg.x = h4.x * sigf(pr.x + br.x + acc[1][i][0]);
        gg.y = h4.y * sigf(pr.y + br.y + acc[1][i][1]);
        gg.z = h4.z * sigf(pr.z + br.z + acc[1][i][2]);
        gg.w = h4.w * sigf(pr.w + br.w + acc[1][i][3]);
        *(float4*)(p.O[0] + idx) = z;
        *(float4*)(p.O[1] + idx) = gg;
      }
    }
  } else {
    float4 bh = *(const float4*)(p.Bv[0] + c0);
#pragma unroll
    for (int i = 0; i < 4; ++i) {
      int nn = n0 + r0 + i;
      if (nn < p.n) {
        size_t idx = (size_t)nn * CH + c0;
        float4 ph = *(const float4*)(p.P[0] + idx);
        float4 z4 = *(const float4*)(p.Zb + idx);
        float4 h4 = *(const float4*)(p.Hb + idx);
        float4 o;
        float t0 = tanhf(ph.x + bh.x + acc[0][i][0]);
        float t1 = tanhf(ph.y + bh.y + acc[0][i][1]);
        float t2 = tanhf(ph.z + bh.z + acc[0][i][2]);
        float t3 = tanhf(ph.w + bh.w + acc[0][i][3]);
        o.x = z4.x * h4.x + (1.f - z4.x) * t0;
        o.y = z4.y * h4.y + (1.f - z4.y) * t1;
        o.z = z4.z * h4.z + (1.f - z4.z) * t2;
        o.w = z4.w * h4.w + (1.f - z4.w) * t3;
        *(float4*)(p.O[0] + idx) = o;
      }
    }
  }
}

// t=0 step: H=0 => cheb(H)=b_h*, so out0 = (1-sig(xzp+b_hz)) * tanh(xhp+b_hh)
__global__ __launch_bounds__(256) void t0_kernel(
    const float4* __restrict__ xzp, const float4* __restrict__ xhp,
    const float* __restrict__ b_hz, const float* __restrict__ b_hh,
    float4* __restrict__ out0, int n4) {
  int i = blockIdx.x * 256 + threadIdx.x;
  if (i >= n4) return;
  int cb = (i << 2) & 63;
  float4 bz = *(const float4*)(b_hz + cb);
  float4 bh = *(const float4*)(b_hh + cb);
  float4 z4 = xzp[i], h4 = xhp[i];
  float4 o;
  o.x = (1.f - sigf(z4.x + bz.x)) * tanhf(h4.x + bh.x);
  o.y = (1.f - sigf(z4.y + bz.y)) * tanhf(h4.y + bh.y);
  o.z = (1.f - sigf(z4.z + bz.z)) * tanhf(h4.z + bh.z);
  o.w = (1.f - sigf(z4.w + bz.w)) * tanhf(h4.w + bh.w);
  out0[i] = o;
}

extern "C" void kernel_launch(void* const* d_in, const int* in_sizes, int n_in,
                              void* d_out, int out_size, void* d_ws, size_t ws_size,
                              hipStream_t stream) {
  const float* X    = (const float*)d_in[0];
  const int*   ei   = (const int*)d_in[1];
  const float* ewt  = (const float*)d_in[2];
  const float* W_xz = (const float*)d_in[3];  const float* b_xz = (const float*)d_in[4];
  const float* W_hz = (const float*)d_in[5];  const float* b_hz = (const float*)d_in[6];
  const float* W_xr = (const float*)d_in[7];  const float* b_xr = (const float*)d_in[8];
  const float* W_hr = (const float*)d_in[9];  const float* b_hr = (const float*)d_in[10];
  const float* W_xh = (const float*)d_in[11]; const float* b_xh = (const float*)d_in[12];
  const float* W_hh = (const float*)d_in[13]; const float* b_hh = (const float*)d_in[14];

  const int N = in_sizes[0] / (SEQLEN * CH);
  const int E = in_sizes[1] / 2;
  const size_t NF = (size_t)N * CH;
  float* out = (float*)d_out;

  char* base = (char*)d_ws;
  size_t off = 0;
  auto take = [&](size_t bytes) -> void* {
    off = (off + 255) & ~(size_t)255;
    void* p = base + off;
    off += bytes;
    return p;
  };
  float* deg   = (float*)take((size_t)N * 4);
  float* dinv  = (float*)take((size_t)N * 4);
  int*   cnt   = (int*)take((size_t)N * 4);
  int*   rowp  = (int*)take((size_t)(N + 1) * 4);
  int*   woff  = (int*)take((size_t)(N + 1) * 4);
  int*   bsum  = (int*)take(1024 * 4);
  int*   ccol  = (int*)take((size_t)E * 4);
  float* cwn   = (float*)take((size_t)E * 4);
  float* t1    = (float*)take(NF * 4);
  float* t2    = (float*)take(NF * 4);
  float* xz    = (float*)take(NF * 4);
  float* xr    = (float*)take(NF * 4);
  float* xh    = (float*)take(NF * 4);
  float* Gb    = (float*)take(NF * 4);
  // tier1: batched X-side Chebyshev bases
  float* t1x = (float*)take(NF * 4 * SEQLEN);
  float* t2x = (float*)take(NF * 4 * SEQLEN);
  size_t off_t1 = off;
  // tier2: batched X-side gate partials
  float* xza = (float*)take(NF * 4 * SEQLEN);
  float* xra = (float*)take(NF * 4 * SEQLEN);
  float* xha = (float*)take(NF * 4 * SEQLEN);
  size_t off_t2 = off;
  (void)n_in; (void)out_size;
  const int tier = (off_t2 <= ws_size) ? 2 : (off_t1 <= ws_size) ? 1 : 0;

  hipMemsetAsync(deg, 0, (size_t)N * 4, stream);
  hipMemsetAsync(cnt, 0, (size_t)N * 4, stream);

  const int ebl = (E + 255) / 256;
  const int nbl = (N + 255) / 256;
  edge_hist_kernel<<<ebl, 256, 0, stream>>>(ei, ewt, deg, cnt, E);
  dinv_kernel<<<nbl, 256, 0, stream>>>(deg, dinv, N);
  scan_part_kernel<<<nbl, 256, 0, stream>>>(cnt, bsum, N);
  scan_top_kernel<<<1, 256, 0, stream>>>(bsum, nbl);
  scan_fill_kernel<<<nbl, 256, 0, stream>>>(cnt, bsum, rowp, woff, N, E);
  scatter_kernel<<<ebl, 256, 0, stream>>>(ei, ewt, dinv, woff, ccol, cwn, E);

  const int nq = (N + 3) / 4;
  const int g3x = (N + 63) / 64;
  const int n4 = (int)(NF / 4);
  const int ewbl = (n4 + 255) / 256;

  if (tier >= 1) {
    spmv_kernel<<<dim3(nq, SEQLEN), 256, 0, stream>>>(
        rowp, ccol, cwn, X, X, t1x, 1.f, 0.f, N, (long long)NF);
    spmv_kernel<<<dim3(nq, SEQLEN), 256, 0, stream>>>(
        rowp, ccol, cwn, t1x, X, t2x, 2.f, -1.f, N, (long long)NF);
  }
  if (tier == 2) {
    FG px = {};
    px.A[0] = X; px.A[1] = t1x; px.A[2] = t2x;
    px.W[0] = W_xz; px.W[1] = W_xr; px.W[2] = W_xh;
    px.Bv[0] = b_xz; px.Bv[1] = b_xr; px.Bv[2] = b_xh;
    px.O[0] = xza; px.O[1] = xra; px.O[2] = xha;
    px.n = N; px.tstride = (long long)NF;
    gemmf_kernel<0, 3><<<dim3(g3x, 1, SEQLEN), 256, 0, stream>>>(px);
  }

  for (int t = 0; t < SEQLEN; ++t) {
    const float* Xt = X + (size_t)t * NF;
    float* outt = out + (size_t)t * NF;
    float* xzp = (tier == 2) ? (xza + (size_t)t * NF) : xz;
    float* xrp = (tier == 2) ? (xra + (size_t)t * NF) : xr;
    float* xhp = (tier == 2) ? (xha + (size_t)t * NF) : xh;

    if (tier < 2) {
      const float* A1 = (tier == 1) ? (t1x + (size_t)t * NF) : t1;
      const float* A2 = (tier == 1) ? (t2x + (size_t)t * NF) : t2;
      if (tier == 0) {
        spmv_kernel<<<dim3(nq, 1), 256, 0, stream>>>(rowp, ccol, cwn, Xt, Xt, t1, 1.f, 0.f, N, 0);
        spmv_kernel<<<dim3(nq, 1), 256, 0, stream>>>(rowp, ccol, cwn, t1, Xt, t2, 2.f, -1.f, N, 0);
      }
      FG px = {};
      px.A[0] = Xt; px.A[1] = A1; px.A[2] = A2;
      px.W[0] = W_xz; px.W[1] = W_xr; px.W[2] = W_xh;
      px.Bv[0] = b_xz; px.Bv[1] = b_xr; px.Bv[2] = b_xh;
      px.O[0] = xzp; px.O[1] = xrp; px.O[2] = xhp;
      px.n = N; px.tstride = 0;
      gemmf_kernel<0, 3><<<dim3(g3x, 1, 1), 256, 0, stream>>>(px);
    }

    if (t == 0) {
      t0_kernel<<<ewbl, 256, 0, stream>>>((const float4*)xzp, (const float4*)xhp,
                                          b_hz, b_hh, (float4*)outt, n4);
      continue;
    }
    const float* H = out + (size_t)(t - 1) * NF;

    // H-side basis + fused (z,r | sigmoid | G=H*R)
    spmv_kernel<<<dim3(nq, 1), 256, 0, stream>>>(rowp, ccol, cwn, H, H, t1, 1.f, 0.f, N, 0);
    spmv_kernel<<<dim3(nq, 1), 256, 0, stream>>>(rowp, ccol, cwn, t1, H, t2, 2.f, -1.f, N, 0);
    FG ph = {};
    ph.A[0] = H; ph.A[1] = t1; ph.A[2] = t2;
    ph.W[0] = W_hz; ph.W[1] = W_hr;
    ph.Bv[0] = b_hz; ph.Bv[1] = b_hr;
    ph.P[0] = xzp; ph.P[1] = xrp;
    ph.Hb = H;
    ph.O[0] = xzp;  // Z (overwrites partial; partial dead after this)
    ph.O[1] = Gb;   // G = H*R
    ph.n = N; ph.tstride = 0;
    gemmf_kernel<1, 2><<<dim3(g3x, 1, 1), 256, 0, stream>>>(ph);

    // (H*R)-side basis + fused (h | tanh | GRU blend) -> outt
    spmv_kernel<<<dim3(nq, 1), 256, 0, stream>>>(rowp, ccol, cwn, Gb, Gb, t1, 1.f, 0.f, N, 0);
    spmv_kernel<<<dim3(nq, 1), 256, 0, stream>>>(rowp, ccol, cwn, t1, Gb, t2, 2.f, -1.f, N, 0);
    FG pg = {};
    pg.A[0] = Gb; pg.A[1] = t1; pg.A[2] = t2;
    pg.W[0] = W_hh;
    pg.Bv[0] = b_hh;
    pg.P[0] = xhp;
    pg.Zb = xzp;  // Z
    pg.Hb = H;
    pg.O[0] = outt;
    pg.n = N; pg.tstride = 0;
    gemmf_kernel<2, 1><<<dim3(g3x, 1, 1), 256, 0, stream>>>(pg);
  }

  // Hlast = States[:, L-1]
  hipMemcpyAsync(out + (size_t)SEQLEN * NF, out + (size_t)(SEQLEN - 1) * NF,
                 NF * 4, hipMemcpyDeviceToDevice, stream);
}

// Round 4
// 2702.940 us; speedup vs baseline: 1.9768x; 1.0158x over previous
//
#include <hip/hip_runtime.h>
#include <cmath>

#define SEQLEN 8
#define CH 64  // IN_CH == HID == 64

typedef unsigned short ushort_t;

__device__ __forceinline__ ushort_t f2bf(float f) {
  union { float f; unsigned u; } v; v.f = f;
  unsigned r = v.u + 0x7fff + ((v.u >> 16) & 1);  // round-nearest-even
  return (ushort_t)(r >> 16);
}
__device__ __forceinline__ float bf2f(ushort_t h) {
  union { unsigned u; float f; } v; v.u = ((unsigned)h) << 16;
  return v.f;
}

// ---- setup: degree + count histogram over rows ----
__global__ __launch_bounds__(256) void edge_hist_kernel(
    const int* __restrict__ ei, const float* __restrict__ ew,
    float* __restrict__ deg, int* __restrict__ cnt, int E) {
  int e = blockIdx.x * 256 + threadIdx.x;
  if (e >= E) return;
  int r = ei[e];
  int c = ei[E + e];
  float wv = (r == c) ? 0.f : ew[e];
  atomicAdd(deg + r, wv);
  atomicAdd(cnt + r, 1);
}

__global__ __launch_bounds__(256) void dinv_kernel(
    const float* __restrict__ deg, float* __restrict__ dinv, int n) {
  int i = blockIdx.x * 256 + threadIdx.x;
  if (i >= n) return;
  float d = deg[i];
  dinv[i] = (d > 0.f) ? (1.0f / sqrtf(d)) : 0.f;
}

// ---- hierarchical scan ----
__global__ __launch_bounds__(256) void scan_part_kernel(
    const int* __restrict__ cnt, int* __restrict__ bsum, int n) {
  int i = blockIdx.x * 256 + threadIdx.x;
  int v = (i < n) ? cnt[i] : 0;
#pragma unroll
  for (int o = 32; o; o >>= 1) v += __shfl_down(v, o, 64);
  __shared__ int red[4];
  if ((threadIdx.x & 63) == 0) red[threadIdx.x >> 6] = v;
  __syncthreads();
  if (threadIdx.x == 0) bsum[blockIdx.x] = red[0] + red[1] + red[2] + red[3];
}

__global__ __launch_bounds__(256) void scan_top_kernel(int* __restrict__ bsum, int nb) {
  int tid = threadIdx.x, lane = tid & 63, wid = tid >> 6;
  int v = (tid < nb) ? bsum[tid] : 0;
  int orig = v;
#pragma unroll
  for (int o = 1; o < 64; o <<= 1) { int t = __shfl_up(v, o, 64); if (lane >= o) v += t; }
  __shared__ int wsum[4];
  if (lane == 63) wsum[wid] = v;
  __syncthreads();
  int base = 0;
  for (int w = 0; w < wid; ++w) base += wsum[w];
  if (tid < nb) bsum[tid] = base + v - orig;
}

__global__ __launch_bounds__(256) void scan_fill_kernel(
    const int* __restrict__ cnt, const int* __restrict__ bsum,
    int* __restrict__ rowp, int* __restrict__ woff, int n, int total) {
  int i = blockIdx.x * 256 + threadIdx.x;
  int tid = threadIdx.x, lane = tid & 63, wid = tid >> 6;
  int v = (i < n) ? cnt[i] : 0;
  int orig = v;
#pragma unroll
  for (int o = 1; o < 64; o <<= 1) { int t = __shfl_up(v, o, 64); if (lane >= o) v += t; }
  __shared__ int wsum[4];
  if (lane == 63) wsum[wid] = v;
  __syncthreads();
  int base = bsum[blockIdx.x];
  for (int w = 0; w < wid; ++w) base += wsum[w];
  if (i < n) { int ex = base + v - orig; rowp[i] = ex; woff[i] = ex; }
  if (blockIdx.x == 0 && tid == 0) rowp[n] = total;
}

__global__ __launch_bounds__(256) void scatter_kernel(
    const int* __restrict__ ei, const float* __restrict__ ew,
    const float* __restrict__ dinv, int* __restrict__ woff,
    int* __restrict__ ccol, float* __restrict__ cwn, int E) {
  int e = blockIdx.x * 256 + threadIdx.x;
  if (e >= E) return;
  int r = ei[e];
  int c = ei[E + e];
  float wv = (r == c) ? 0.f : ew[e];
  float wn = -wv * dinv[r] * dinv[c];
  int pos = atomicAdd(woff + r, 1);
  ccol[pos] = c;
  cwn[pos] = wn;
}

// fp32 -> bf16 bulk convert (for X slabs)
__global__ __launch_bounds__(256) void cvt_bf_kernel(
    const float4* __restrict__ in, ushort_t* __restrict__ outb, long long n4) {
  long long i = (long long)blockIdx.x * 256 + threadIdx.x;
  if (i >= n4) return;
  float4 v = in[i];
  ushort_t* o = outb + i * 4;
  o[0] = f2bf(v.x); o[1] = f2bf(v.y); o[2] = f2bf(v.z); o[3] = f2bf(v.w);
}

// ---- SpMV, fp32 payload (fallback) ----
__global__ __launch_bounds__(256) void spmv_kernel(
    const int* __restrict__ rowp, const int* __restrict__ ccol,
    const float* __restrict__ cwn, const float* __restrict__ v,
    const float* __restrict__ u, float* __restrict__ y,
    float alpha, float beta, int n, long long slab_stride) {
  int r = blockIdx.x * 4 + (threadIdx.x >> 6);
  if (r >= n) return;
  long long so = (long long)blockIdx.y * slab_stride;
  const float* __restrict__ vs = v + so;
  const float* __restrict__ us = u + so;
  float* __restrict__ ys = y + so;
  int lane = threadIdx.x & 63;
  int s = __builtin_amdgcn_readfirstlane(rowp[r]);
  int e = __builtin_amdgcn_readfirstlane(rowp[r + 1]);
  float a0 = 0.f, a1 = 0.f, a2 = 0.f, a3 = 0.f;
  int i = s;
  for (; i + 4 <= e; i += 4) {
    int c0 = ccol[i], c1 = ccol[i + 1], c2 = ccol[i + 2], c3 = ccol[i + 3];
    float w0 = cwn[i], w1 = cwn[i + 1], w2 = cwn[i + 2], w3 = cwn[i + 3];
    float x0 = vs[(size_t)c0 * CH + lane];
    float x1 = vs[(size_t)c1 * CH + lane];
    float x2 = vs[(size_t)c2 * CH + lane];
    float x3 = vs[(size_t)c3 * CH + lane];
    a0 = fmaf(w0, x0, a0); a1 = fmaf(w1, x1, a1);
    a2 = fmaf(w2, x2, a2); a3 = fmaf(w3, x3, a3);
  }
  for (; i < e; ++i) a0 = fmaf(cwn[i], vs[(size_t)ccol[i] * CH + lane], a0);
  float res = alpha * ((a0 + a1) + (a2 + a3));
  if (beta != 0.f) res += beta * us[(size_t)r * CH + lane];
  ys[(size_t)r * CH + lane] = res;
}

// ---- SpMV, bf16 gather payload (halves L2-fill traffic) ----
// y (fp32) always written; yb (bf16 shadow for a subsequent gather) optional.
__global__ __launch_bounds__(256) void spmv_bf_kernel(
    const int* __restrict__ rowp, const int* __restrict__ ccol,
    const float* __restrict__ cwn, const ushort_t* __restrict__ v,
    const float* __restrict__ u, float* __restrict__ y, ushort_t* __restrict__ yb,
    float alpha, float beta, int n, long long slab_stride) {
  int r = blockIdx.x * 4 + (threadIdx.x >> 6);
  if (r >= n) return;
  long long so = (long long)blockIdx.y * slab_stride;
  const ushort_t* __restrict__ vs = v + so;
  const float* __restrict__ us = u + so;
  float* __restrict__ ys = y + so;
  int lane = threadIdx.x & 63;
  int s = __builtin_amdgcn_readfirstlane(rowp[r]);
  int e = __builtin_amdgcn_readfirstlane(rowp[r + 1]);
  float a0 = 0.f, a1 = 0.f, a2 = 0.f, a3 = 0.f;
  int i = s;
  for (; i + 4 <= e; i += 4) {
    int c0 = ccol[i], c1 = ccol[i + 1], c2 = ccol[i + 2], c3 = ccol[i + 3];
    float w0 = cwn[i], w1 = cwn[i + 1], w2 = cwn[i + 2], w3 = cwn[i + 3];
    float x0 = bf2f(vs[(size_t)c0 * CH + lane]);
    float x1 = bf2f(vs[(size_t)c1 * CH + lane]);
    float x2 = bf2f(vs[(size_t)c2 * CH + lane]);
    float x3 = bf2f(vs[(size_t)c3 * CH + lane]);
    a0 = fmaf(w0, x0, a0); a1 = fmaf(w1, x1, a1);
    a2 = fmaf(w2, x2, a2); a3 = fmaf(w3, x3, a3);
  }
  for (; i < e; ++i) a0 = fmaf(cwn[i], bf2f(vs[(size_t)ccol[i] * CH + lane]), a0);
  float res = alpha * ((a0 + a1) + (a2 + a3));
  if (beta != 0.f) res += beta * us[(size_t)r * CH + lane];
  size_t oi = (size_t)r * CH + lane;
  ys[oi] = res;
  if (yb) yb[so + oi] = f2bf(res);
}

// ---- fused multi-gate GEMM ----
struct FG {
  const float* A[3];
  const float* W[3];
  const float* Bv[3];
  const float* P[3];
  const float* Hb;
  const float* Zb;
  float* O[3];
  ushort_t* OB0;  // optional bf16 shadow: MODE1 -> of O[1]; MODE2 -> of O[0]
  int n;
  long long tstride;
};

__device__ __forceinline__ void fma_tile(float (&acc)[4][4], const float* At,
                                         const float* Wt, int r0, int c0) {
#pragma unroll 4
  for (int k = 0; k < 64; ++k) {
    float4 a = *(const float4*)(At + k * 68 + r0);
    float4 w = *(const float4*)(Wt + k * 64 + c0);
    float av[4] = { a.x, a.y, a.z, a.w };
    float wv[4] = { w.x, w.y, w.z, w.w };
#pragma unroll
    for (int i = 0; i < 4; ++i)
#pragma unroll
      for (int j = 0; j < 4; ++j)
        acc[i][j] = fmaf(av[i], wv[j], acc[i][j]);
  }
}

__device__ __forceinline__ float sigf(float x) { return 1.f / (1.f + expf(-x)); }

template <int MODE, int G>
__global__ __launch_bounds__(256) void gemmf_kernel(FG p) {
  __shared__ float At[64 * 68];
  __shared__ float Wt[64 * 64];
  const int tid = threadIdx.x;
  const int n0 = blockIdx.x * 64;
  const int r0 = (tid >> 4) << 2;
  const int c0 = (tid & 15) << 2;
  const long long toff = (long long)blockIdx.z * p.tstride;
  float acc[G][4][4];
#pragma unroll
  for (int g = 0; g < G; ++g)
#pragma unroll
    for (int i = 0; i < 4; ++i)
#pragma unroll
      for (int j = 0; j < 4; ++j) acc[g][i][j] = 0.f;

  for (int kk = 0; kk < 3; ++kk) {
    const float* __restrict__ A = p.A[kk] + toff;
    __syncthreads();
#pragma unroll
    for (int j = 0; j < 4; ++j) {
      int flat = tid + 256 * j;
      int r = flat >> 4;
      int k4 = (flat & 15) << 2;
      int nn = n0 + r;
      float4 av = (nn < p.n) ? *(const float4*)(A + (size_t)nn * CH + k4)
                             : make_float4(0.f, 0.f, 0.f, 0.f);
      At[(k4 + 0) * 68 + r] = av.x;
      At[(k4 + 1) * 68 + r] = av.y;
      At[(k4 + 2) * 68 + r] = av.z;
      At[(k4 + 3) * 68 + r] = av.w;
    }
#pragma unroll
    for (int g = 0; g < G; ++g) {
      if (g > 0) __syncthreads();
      const float* __restrict__ Wk = p.W[g] + kk * 4096;
#pragma unroll
      for (int j = 0; j < 4; ++j) {
        int flat = tid + 256 * j;
        *(float4*)(Wt + flat * 4) = *(const float4*)(Wk + flat * 4);
      }
      __syncthreads();
      fma_tile(acc[g], At, Wt, r0, c0);
    }
  }

  if (MODE == 0) {
#pragma unroll
    for (int g = 0; g < G; ++g) {
      float4 bv = *(const float4*)(p.Bv[g] + c0);
      float* og = p.O[g] + toff;
#pragma unroll
      for (int i = 0; i < 4; ++i) {
        int nn = n0 + r0 + i;
        if (nn < p.n) {
          float4 o;
          o.x = acc[g][i][0] + bv.x;
          o.y = acc[g][i][1] + bv.y;
          o.z = acc[g][i][2] + bv.z;
          o.w = acc[g][i][3] + bv.w;
          *(float4*)(og + (size_t)nn * CH + c0) = o;
        }
      }
    }
  } else if (MODE == 1) {
    float4 bz = *(const float4*)(p.Bv[0] + c0);
    float4 br = *(const float4*)(p.Bv[1] + c0);
#pragma unroll
    for (int i = 0; i < 4; ++i) {
      int nn = n0 + r0 + i;
      if (nn < p.n) {
        size_t idx = (size_t)nn * CH + c0;
        float4 pz = *(const float4*)(p.P[0] + idx);
        float4 pr = *(const float4*)(p.P[1] + idx);
        float4 h4 = *(const float4*)(p.Hb + idx);
        float4 z, gg;
        z.x = sigf(pz.x + bz.x + acc[0][i][0]);
        z.y = sigf(pz.y + bz.y + acc[0][i][1]);
        z.z = sigf(pz.z + bz.z + acc[0][i][2]);
        z.w = sigf(pz.w + bz.w + acc[0][i][3]);
        gg.x = h4.x * sigf(pr.x + br.x + acc[1][i][0]);
        gg.y = h4.y * sigf(pr.y + br.y + acc[1][i][1]);
        gg.z = h4.z * sigf(pr.z + br.z + acc[1][i][2]);
        gg.w = h4.w * sigf(pr.w + br.w + acc[1][i][3]);
        *(float4*)(p.O[0] + idx) = z;
        *(float4*)(p.O[1] + idx) = gg;
        if (p.OB0) {
          ushort_t* ob = p.OB0 + idx;
          ob[0] = f2bf(gg.x); ob[1] = f2bf(gg.y);
          ob[2] = f2bf(gg.z); ob[3] = f2bf(gg.w);
        }
      }
    }
  } else {
    float4 bh = *(const float4*)(p.Bv[0] + c0);
#pragma unroll
    for (int i = 0; i < 4; ++i) {
      int nn = n0 + r0 + i;
      if (nn < p.n) {
        size_t idx = (size_t)nn * CH + c0;
        float4 ph = *(const float4*)(p.P[0] + idx);
        float4 z4 = *(const float4*)(p.Zb + idx);
        float4 h4 = *(const float4*)(p.Hb + idx);
        float4 o;
        float t0 = tanhf(ph.x + bh.x + acc[0][i][0]);
        float t1 = tanhf(ph.y + bh.y + acc[0][i][1]);
        float t2 = tanhf(ph.z + bh.z + acc[0][i][2]);
        float t3 = tanhf(ph.w + bh.w + acc[0][i][3]);
        o.x = z4.x * h4.x + (1.f - z4.x) * t0;
        o.y = z4.y * h4.y + (1.f - z4.y) * t1;
        o.z = z4.z * h4.z + (1.f - z4.z) * t2;
        o.w = z4.w * h4.w + (1.f - z4.w) * t3;
        *(float4*)(p.O[0] + idx) = o;
        if (p.OB0) {
          ushort_t* ob = p.OB0 + idx;
          ob[0] = f2bf(o.x); ob[1] = f2bf(o.y);
          ob[2] = f2bf(o.z); ob[3] = f2bf(o.w);
        }
      }
    }
  }
}

// t=0: H=0 => out0 = (1-sig(xzp+b_hz)) * tanh(xhp+b_hh); also bf16 shadow for step 1
__global__ __launch_bounds__(256) void t0_kernel(
    const float4* __restrict__ xzp, const float4* __restrict__ xhp,
    const float* __restrict__ b_hz, const float* __restrict__ b_hh,
    float4* __restrict__ out0, ushort_t* __restrict__ out0b, int n4) {
  int i = blockIdx.x * 256 + threadIdx.x;
  if (i >= n4) return;
  int cb = (i << 2) & 63;
  float4 bz = *(const float4*)(b_hz + cb);
  float4 bh = *(const float4*)(b_hh + cb);
  float4 z4 = xzp[i], h4 = xhp[i];
  float4 o;
  o.x = (1.f - sigf(z4.x + bz.x)) * tanhf(h4.x + bh.x);
  o.y = (1.f - sigf(z4.y + bz.y)) * tanhf(h4.y + bh.y);
  o.z = (1.f - sigf(z4.z + bz.z)) * tanhf(h4.z + bh.z);
  o.w = (1.f - sigf(z4.w + bz.w)) * tanhf(h4.w + bh.w);
  out0[i] = o;
  if (out0b) {
    ushort_t* ob = out0b + (size_t)i * 4;
    ob[0] = f2bf(o.x); ob[1] = f2bf(o.y); ob[2] = f2bf(o.z); ob[3] = f2bf(o.w);
  }
}

extern "C" void kernel_launch(void* const* d_in, const int* in_sizes, int n_in,
                              void* d_out, int out_size, void* d_ws, size_t ws_size,
                              hipStream_t stream) {
  const float* X    = (const float*)d_in[0];
  const int*   ei   = (const int*)d_in[1];
  const float* ewt  = (const float*)d_in[2];
  const float* W_xz = (const float*)d_in[3];  const float* b_xz = (const float*)d_in[4];
  const float* W_hz = (const float*)d_in[5];  const float* b_hz = (const float*)d_in[6];
  const float* W_xr = (const float*)d_in[7];  const float* b_xr = (const float*)d_in[8];
  const float* W_hr = (const float*)d_in[9];  const float* b_hr = (const float*)d_in[10];
  const float* W_xh = (const float*)d_in[11]; const float* b_xh = (const float*)d_in[12];
  const float* W_hh = (const float*)d_in[13]; const float* b_hh = (const float*)d_in[14];

  const int N = in_sizes[0] / (SEQLEN * CH);
  const int E = in_sizes[1] / 2;
  const size_t NF = (size_t)N * CH;
  float* out = (float*)d_out;

  char* base = (char*)d_ws;
  size_t off = 0;
  auto take = [&](size_t bytes) -> void* {
    off = (off + 255) & ~(size_t)255;
    void* p = base + off;
    off += bytes;
    return p;
  };
  float* deg   = (float*)take((size_t)N * 4);
  float* dinv  = (float*)take((size_t)N * 4);
  int*   cnt   = (int*)take((size_t)N * 4);
  int*   rowp  = (int*)take((size_t)(N + 1) * 4);
  int*   woff  = (int*)take((size_t)(N + 1) * 4);
  int*   bsum  = (int*)take(1024 * 4);
  int*   ccol  = (int*)take((size_t)E * 4);
  float* cwn   = (float*)take((size_t)E * 4);
  float* t1    = (float*)take(NF * 4);
  float* t2    = (float*)take(NF * 4);
  float* xz    = (float*)take(NF * 4);
  float* xr    = (float*)take(NF * 4);
  float* xh    = (float*)take(NF * 4);
  float* Gb    = (float*)take(NF * 4);
  // tier1: batched X-side Chebyshev bases
  float* t1x = (float*)take(NF * 4 * SEQLEN);
  float* t2x = (float*)take(NF * 4 * SEQLEN);
  size_t off_t1 = off;
  // tier2: batched X-side gate partials
  float* xza = (float*)take(NF * 4 * SEQLEN);
  float* xra = (float*)take(NF * 4 * SEQLEN);
  float* xha = (float*)take(NF * 4 * SEQLEN);
  size_t off_t2 = off;
  // bf16 gather shadows
  ushort_t* Xb   = (ushort_t*)take(NF * 2 * SEQLEN);
  ushort_t* t1xb = (ushort_t*)take(NF * 2 * SEQLEN);
  ushort_t* Hbb  = (ushort_t*)take(NF * 2);
  ushort_t* Gbb  = (ushort_t*)take(NF * 2);
  ushort_t* t1b  = (ushort_t*)take(NF * 2);
  size_t off_bf = off;
  (void)n_in; (void)out_size;
  const int tier = (off_t2 <= ws_size) ? 2 : (off_t1 <= ws_size) ? 1 : 0;
  const bool useBF = (tier == 2) && (off_bf <= ws_size);

  hipMemsetAsync(deg, 0, (size_t)N * 4, stream);
  hipMemsetAsync(cnt, 0, (size_t)N * 4, stream);

  const int ebl = (E + 255) / 256;
  const int nbl = (N + 255) / 256;
  edge_hist_kernel<<<ebl, 256, 0, stream>>>(ei, ewt, deg, cnt, E);
  dinv_kernel<<<nbl, 256, 0, stream>>>(deg, dinv, N);
  scan_part_kernel<<<nbl, 256, 0, stream>>>(cnt, bsum, N);
  scan_top_kernel<<<1, 256, 0, stream>>>(bsum, nbl);
  scan_fill_kernel<<<nbl, 256, 0, stream>>>(cnt, bsum, rowp, woff, N, E);
  scatter_kernel<<<ebl, 256, 0, stream>>>(ei, ewt, dinv, woff, ccol, cwn, E);

  const int nq = (N + 3) / 4;
  const int g3x = (N + 63) / 64;
  const int n4 = (int)(NF / 4);
  const int ewbl = (n4 + 255) / 256;

  if (useBF) {
    long long xn4 = (long long)(NF * SEQLEN / 4);
    cvt_bf_kernel<<<(int)((xn4 + 255) / 256), 256, 0, stream>>>((const float4*)X, Xb, xn4);
    spmv_bf_kernel<<<dim3(nq, SEQLEN), 256, 0, stream>>>(
        rowp, ccol, cwn, Xb, X, t1x, t1xb, 1.f, 0.f, N, (long long)NF);
    spmv_bf_kernel<<<dim3(nq, SEQLEN), 256, 0, stream>>>(
        rowp, ccol, cwn, t1xb, X, t2x, nullptr, 2.f, -1.f, N, (long long)NF);
  } else if (tier >= 1) {
    spmv_kernel<<<dim3(nq, SEQLEN), 256, 0, stream>>>(
        rowp, ccol, cwn, X, X, t1x, 1.f, 0.f, N, (long long)NF);
    spmv_kernel<<<dim3(nq, SEQLEN), 256, 0, stream>>>(
        rowp, ccol, cwn, t1x, X, t2x, 2.f, -1.f, N, (long long)NF);
  }
  if (tier == 2) {
    FG px = {};
    px.A[0] = X; px.A[1] = t1x; px.A[2] = t2x;
    px.W[0] = W_xz; px.W[1] = W_xr; px.W[2] = W_xh;
    px.Bv[0] = b_xz; px.Bv[1] = b_xr; px.Bv[2] = b_xh;
    px.O[0] = xza; px.O[1] = xra; px.O[2] = xha;
    px.n = N; px.tstride = (long long)NF;
    gemmf_kernel<0, 3><<<dim3(g3x, 1, SEQLEN), 256, 0, stream>>>(px);
  }

  for (int t = 0; t < SEQLEN; ++t) {
    const float* Xt = X + (size_t)t * NF;
    float* outt = out + (size_t)t * NF;
    float* xzp = (tier == 2) ? (xza + (size_t)t * NF) : xz;
    float* xrp = (tier == 2) ? (xra + (size_t)t * NF) : xr;
    float* xhp = (tier == 2) ? (xha + (size_t)t * NF) : xh;

    if (tier < 2) {
      const float* A1 = (tier == 1) ? (t1x + (size_t)t * NF) : t1;
      const float* A2 = (tier == 1) ? (t2x + (size_t)t * NF) : t2;
      if (tier == 0) {
        spmv_kernel<<<dim3(nq, 1), 256, 0, stream>>>(rowp, ccol, cwn, Xt, Xt, t1, 1.f, 0.f, N, 0);
        spmv_kernel<<<dim3(nq, 1), 256, 0, stream>>>(rowp, ccol, cwn, t1, Xt, t2, 2.f, -1.f, N, 0);
      }
      FG px = {};
      px.A[0] = Xt; px.A[1] = A1; px.A[2] = A2;
      px.W[0] = W_xz; px.W[1] = W_xr; px.W[2] = W_xh;
      px.Bv[0] = b_xz; px.Bv[1] = b_xr; px.Bv[2] = b_xh;
      px.O[0] = xzp; px.O[1] = xrp; px.O[2] = xhp;
      px.n = N; px.tstride = 0;
      gemmf_kernel<0, 3><<<dim3(g3x, 1, 1), 256, 0, stream>>>(px);
    }

    if (t == 0) {
      t0_kernel<<<ewbl, 256, 0, stream>>>((const float4*)xzp, (const float4*)xhp,
                                          b_hz, b_hh, (float4*)outt,
                                          useBF ? Hbb : nullptr, n4);
      continue;
    }
    const float* H = out + (size_t)(t - 1) * NF;

    // H-side basis + fused (z,r | sigmoid | G=H*R)
    if (useBF) {
      spmv_bf_kernel<<<dim3(nq, 1), 256, 0, stream>>>(rowp, ccol, cwn, Hbb, H, t1, t1b, 1.f, 0.f, N, 0);
      spmv_bf_kernel<<<dim3(nq, 1), 256, 0, stream>>>(rowp, ccol, cwn, t1b, H, t2, nullptr, 2.f, -1.f, N, 0);
    } else {
      spmv_kernel<<<dim3(nq, 1), 256, 0, stream>>>(rowp, ccol, cwn, H, H, t1, 1.f, 0.f, N, 0);
      spmv_kernel<<<dim3(nq, 1), 256, 0, stream>>>(rowp, ccol, cwn, t1, H, t2, 2.f, -1.f, N, 0);
    }
    FG ph = {};
    ph.A[0] = H; ph.A[1] = t1; ph.A[2] = t2;
    ph.W[0] = W_hz; ph.W[1] = W_hr;
    ph.Bv[0] = b_hz; ph.Bv[1] = b_hr;
    ph.P[0] = xzp; ph.P[1] = xrp;
    ph.Hb = H;
    ph.O[0] = xzp;  // Z
    ph.O[1] = Gb;   // G = H*R
    ph.OB0 = useBF ? Gbb : nullptr;
    ph.n = N; ph.tstride = 0;
    gemmf_kernel<1, 2><<<dim3(g3x, 1, 1), 256, 0, stream>>>(ph);

    // (H*R)-side basis + fused (h | tanh | GRU blend) -> outt (+ bf16 H shadow)
    if (useBF) {
      spmv_bf_kernel<<<dim3(nq, 1), 256, 0, stream>>>(rowp, ccol, cwn, Gbb, Gb, t1, t1b, 1.f, 0.f, N, 0);
      spmv_bf_kernel<<<dim3(nq, 1), 256, 0, stream>>>(rowp, ccol, cwn, t1b, Gb, t2, nullptr, 2.f, -1.f, N, 0);
    } else {
      spmv_kernel<<<dim3(nq, 1), 256, 0, stream>>>(rowp, ccol, cwn, Gb, Gb, t1, 1.f, 0.f, N, 0);
      spmv_kernel<<<dim3(nq, 1), 256, 0, stream>>>(rowp, ccol, cwn, t1, Gb, t2, 2.f, -1.f, N, 0);
    }
    FG pg = {};
    pg.A[0] = Gb; pg.A[1] = t1; pg.A[2] = t2;
    pg.W[0] = W_hh;
    pg.Bv[0] = b_hh;
    pg.P[0] = xhp;
    pg.Zb = xzp;
    pg.Hb = H;
    pg.O[0] = outt;
    pg.OB0 = (useBF && t < SEQLEN - 1) ? Hbb : nullptr;
    pg.n = N; pg.tstride = 0;
    gemmf_kernel<2, 1><<<dim3(g3x, 1, 1), 256, 0, stream>>>(pg);
  }

  // Hlast = States[:, L-1]
  hipMemcpyAsync(out + (size_t)SEQLEN * NF, out + (size_t)(SEQLEN - 1) * NF,
                 NF * 4, hipMemcpyDeviceToDevice, stream);
}